// Round 6
// baseline (613.400 us; speedup 1.0000x reference)
//
#include <hip/hip_runtime.h>
#include <hip/hip_bf16.h>

typedef __bf16 bf16_t;
typedef __bf16 bf16x4 __attribute__((ext_vector_type(4)));
typedef __bf16 bf16x8 __attribute__((ext_vector_type(8)));
typedef float f32x4 __attribute__((ext_vector_type(4)));

#define SCALE 0.08838834764831845f
#define NEG_MASK -1e10f      // matches reference; exp underflows to exact 0
#define NEG_INIT -3e38f      // running-max init; finite so no inf-inf paths

constexpr int H_ = 16;
constexpr int KH_ = 4;
constexpr int D_ = 128;
constexpr int BM = 64;   // q rows per workgroup
constexpr int BN = 64;   // keys per tile

// LDS strides in bf16 elements; multiples of 4 (8B) keep stores aligned,
// +8 pad breaks power-of-2 bank aliasing for the b128 fragment reads.
constexpr int K_STRIDE = 136;  // K tile [64][128]+pad
constexpr int V_STRIDE = 72;   // V^T tile [128][64]+pad
constexpr int P_STRIDE = 72;   // per-wave P tile [16][64]+pad

// Inputs fp32 (R5: bf16 view NaNs -> fp32 storage proven).
// Output fp32 (reference returns fp32; harness contract: out follows
// reference dtype. R0-R4's bf16 stores into the fp32 buffer scrambled the
// comparison -> absmax 4.75 > max|ref|; both implementations were right.)
__global__ __launch_bounds__(256)
void fa_fwd(const float* __restrict__ qg,
            const float* __restrict__ kg,
            const float* __restrict__ vg,
            float* __restrict__ og,
            int S)
{
    const int qt  = blockIdx.x;          // q tile within sequence
    const int h   = blockIdx.y;
    const int b   = blockIdx.z;
    const int kh  = h / (H_ / KH_);      // GQA: 4 q-heads share one kv-head

    const int tid  = threadIdx.x;
    const int wid  = tid >> 6;
    const int lane = tid & 63;
    const int quad = lane >> 4;
    const int l16  = lane & 15;

    __shared__ bf16_t lds_k[BN * K_STRIDE];
    __shared__ bf16_t lds_v[D_ * V_STRIDE];      // transposed: [d][key]
    __shared__ bf16_t lds_p[4 * 16 * P_STRIDE];  // per-wave P staging

    const int  q0   = qt * BM;
    const long tok0 = (long)b * S;

    // ---- Q fragments (A-layout): fp32 global load, cvt to bf16 in-register.
    bf16x8 qfrag[4];
    {
        const long row = tok0 + q0 + wid * 16 + l16;
        const float* qp = qg + (row * H_ + h) * D_;
        #pragma unroll
        for (int kc = 0; kc < 4; ++kc) {
            f32x4 a = *reinterpret_cast<const f32x4*>(qp + kc * 32 + quad * 8);
            f32x4 c = *reinterpret_cast<const f32x4*>(qp + kc * 32 + quad * 8 + 4);
            #pragma unroll
            for (int j = 0; j < 4; ++j) {
                qfrag[kc][j]     = (bf16_t)a[j];
                qfrag[kc][j + 4] = (bf16_t)c[j];
            }
        }
    }

    f32x4 oacc[8];                        // O[16][128] in C-layout, 8 d-tiles
    #pragma unroll
    for (int i = 0; i < 8; ++i) oacc[i] = (f32x4){0.f, 0.f, 0.f, 0.f};
    float m_i[4], l_i[4];                 // per C-row (row = quad*4 + r)
    #pragma unroll
    for (int r = 0; r < 4; ++r) { m_i[r] = NEG_INIT; l_i[r] = 0.f; }

    const int nkt = qt + 1;               // causal: only tiles up to diagonal
    for (int kt = 0; kt < nkt; ++kt) {
        const int kst = kt * BN;
        __syncthreads();                  // prior iter's LDS reads done

        // ---- stage K tile [64][128]: fp32 float4 loads -> bf16x4 LDS stores
        #pragma unroll
        for (int it = 0; it < 8; ++it) {
            int c = it * 256 + tid;       // 0..2047
            int n = c >> 5, ch = c & 31;  // row 0..63, float4-chunk 0..31
            long row = tok0 + kst + n;
            f32x4 t = *reinterpret_cast<const f32x4*>(
                kg + (row * KH_ + kh) * D_ + ch * 4);
            bf16x4 w;
            w[0] = (bf16_t)t[0]; w[1] = (bf16_t)t[1];
            w[2] = (bf16_t)t[2]; w[3] = (bf16_t)t[3];
            *reinterpret_cast<bf16x4*>(&lds_k[n * K_STRIDE + ch * 4]) = w;
        }
        // ---- stage V transposed: lds_v[d][key]; float4 load, bf16 scatter
        {
            int n = tid & 63;
            long row = tok0 + kst + n;
            const float* vp = vg + (row * KH_ + kh) * D_;
            #pragma unroll
            for (int it = 0; it < 8; ++it) {
                int dch = (tid >> 6) * 8 + it;   // 0..31, d = dch*4..+3
                f32x4 t = *reinterpret_cast<const f32x4*>(vp + dch * 4);
                #pragma unroll
                for (int j = 0; j < 4; ++j)
                    lds_v[(dch * 4 + j) * V_STRIDE + n] = (bf16_t)t[j];
            }
        }
        __syncthreads();

        // ---- S = Q K^T  (per wave: 16 rows x 64 keys)
        f32x4 s[4];
        #pragma unroll
        for (int nt = 0; nt < 4; ++nt) {
            f32x4 acc = (f32x4){0.f, 0.f, 0.f, 0.f};
            #pragma unroll
            for (int kc = 0; kc < 4; ++kc) {
                bf16x8 kf = *reinterpret_cast<const bf16x8*>(
                    &lds_k[(nt * 16 + l16) * K_STRIDE + kc * 32 + quad * 8]);
                acc = __builtin_amdgcn_mfma_f32_16x16x32_bf16(qfrag[kc], kf, acc, 0, 0, 0);
            }
            s[nt] = acc;
        }

        // ---- online softmax (per C-row; 16-lane butterfly within quad)
        const int  row_base = q0 + wid * 16 + quad * 4;
        const bool diag = (kst + BN > q0);   // only diagonal tile needs mask
        float alpha[4];
        #pragma unroll
        for (int r = 0; r < 4; ++r) {
            const int rowg = row_base + r;
            #pragma unroll
            for (int nt = 0; nt < 4; ++nt) {
                float x = s[nt][r] * SCALE;
                if (diag && (kst + nt * 16 + l16 > rowg)) x = NEG_MASK;
                s[nt][r] = x;
            }
            float mx = fmaxf(fmaxf(s[0][r], s[1][r]), fmaxf(s[2][r], s[3][r]));
            mx = fmaxf(mx, __shfl_xor(mx, 1));
            mx = fmaxf(mx, __shfl_xor(mx, 2));
            mx = fmaxf(mx, __shfl_xor(mx, 4));
            mx = fmaxf(mx, __shfl_xor(mx, 8));
            const float mn = fmaxf(m_i[r], mx);
            alpha[r] = __expf(m_i[r] - mn);
            float rs = 0.f;
            #pragma unroll
            for (int nt = 0; nt < 4; ++nt) {
                float p = __expf(s[nt][r] - mn);
                s[nt][r] = p;
                rs += p;
            }
            rs += __shfl_xor(rs, 1);
            rs += __shfl_xor(rs, 2);
            rs += __shfl_xor(rs, 4);
            rs += __shfl_xor(rs, 8);
            l_i[r] = l_i[r] * alpha[r] + rs;
            m_i[r] = mn;
        }
        #pragma unroll
        for (int dt = 0; dt < 8; ++dt)
            #pragma unroll
            for (int r = 0; r < 4; ++r)
                oacc[dt][r] *= alpha[r];

        // ---- P: C-layout -> A-layout via per-wave LDS round-trip.
        // PV's ds_read consumes OTHER lanes' writes; barrier makes the
        // cross-lane dependency explicit.
        bf16_t* pw = &lds_p[wid * 16 * P_STRIDE];
        #pragma unroll
        for (int nt = 0; nt < 4; ++nt)
            #pragma unroll
            for (int r = 0; r < 4; ++r)
                pw[(quad * 4 + r) * P_STRIDE + nt * 16 + l16] = (bf16_t)s[nt][r];
        __syncthreads();

        // ---- O += P V
        #pragma unroll
        for (int kc = 0; kc < 2; ++kc) {
            bf16x8 pf = *reinterpret_cast<const bf16x8*>(
                &pw[l16 * P_STRIDE + kc * 32 + quad * 8]);
            #pragma unroll
            for (int dt = 0; dt < 8; ++dt) {
                bf16x8 vf = *reinterpret_cast<const bf16x8*>(
                    &lds_v[(dt * 16 + l16) * V_STRIDE + kc * 32 + quad * 8]);
                oacc[dt] = __builtin_amdgcn_mfma_f32_16x16x32_bf16(pf, vf, oacc[dt], 0, 0, 0);
            }
        }
    }

    // ---- epilogue: O /= l, store FP32
    const long orow0 = tok0 + q0 + wid * 16;
    #pragma unroll
    for (int r = 0; r < 4; ++r) {
        const float inv = 1.0f / l_i[r];
        float* op = og + ((orow0 + quad * 4 + r) * H_ + h) * D_;
        #pragma unroll
        for (int dt = 0; dt < 8; ++dt)
            op[dt * 16 + l16] = oacc[dt][r] * inv;
    }
}

extern "C" void kernel_launch(void* const* d_in, const int* in_sizes, int n_in,
                              void* d_out, int out_size, void* d_ws, size_t ws_size,
                              hipStream_t stream) {
    const float* q = (const float*)d_in[0];   // fp32 (proven R5)
    const float* k = (const float*)d_in[1];
    const float* v = (const float*)d_in[2];
    float* out = (float*)d_out;               // fp32, per reference dtype

    const int B = in_sizes[3] - 1;
    const int T = in_sizes[0] / (H_ * D_);
    const int S = T / B;

    dim3 grid(S / BM, H_, B);
    fa_fwd<<<grid, 256, 0, stream>>>(q, k, v, out, S);
}